// Round 2
// baseline (1463.841 us; speedup 1.0000x reference)
//
#include <hip/hip_runtime.h>
#include <cstdint>
#include <cstddef>

// Problem constants (fixed by the reference)
#define NN 50000
#define EE 400000
#define FIN 128
#define HH 3
#define DD 64
#define GG 64
#define PP 64
#define HD 192   // H*D

__device__ inline float wsum(float v) {
#pragma unroll
    for (int m = 32; m > 0; m >>= 1) v += __shfl_xor(v, m, 64);
    return v;
}
__device__ inline float wmax(float v) {
#pragma unroll
    for (int m = 32; m > 0; m >>= 1) v = fmaxf(v, __shfl_xor(v, m, 64));
    return v;
}

// ---------------- CSR build ----------------
__global__ void k_count(const int* __restrict__ dst, int* __restrict__ counts) {
    int e = blockIdx.x * 256 + threadIdx.x;
    if (e < EE) atomicAdd(&counts[dst[e]], 1);
}

__global__ void k_scan_block(const int* __restrict__ in, int* __restrict__ out,
                             int* __restrict__ bsums) {
    __shared__ int tmp[1024];
    int tid = threadIdx.x;
    int i = blockIdx.x * 1024 + tid;
    int v = (i < NN) ? in[i] : 0;
    tmp[tid] = v;
    __syncthreads();
    for (int off = 1; off < 1024; off <<= 1) {
        int t = (tid >= off) ? tmp[tid - off] : 0;
        __syncthreads();
        tmp[tid] += t;
        __syncthreads();
    }
    if (i < NN) out[i] = tmp[tid] - v;       // exclusive within block
    if (tid == 1023) bsums[blockIdx.x] = tmp[1023];
}

__global__ void k_scan_top(int* bsums, int nb) {
    int lane = threadIdx.x;
    int v = (lane < nb) ? bsums[lane] : 0;
    int x = v;
    for (int off = 1; off < 64; off <<= 1) {
        int t = __shfl_up(x, off, 64);
        if (lane >= off) x += t;
    }
    if (lane < nb) bsums[lane] = x - v;      // exclusive
}

__global__ void k_scan_add(int* __restrict__ row_ptr, const int* __restrict__ bsums) {
    int i = blockIdx.x * 1024 + threadIdx.x;
    if (i < NN) row_ptr[i] += bsums[blockIdx.x];
    if (blockIdx.x == 0 && threadIdx.x == 0) row_ptr[NN] = EE;
}

__global__ void k_scatter(const int* __restrict__ src, const int* __restrict__ dst,
                          const int* __restrict__ row_ptr, int* __restrict__ cursor,
                          int* __restrict__ csr_src, int* __restrict__ csr_dst) {
    int e = blockIdx.x * 256 + threadIdx.x;
    if (e >= EE) return;
    int v = dst[e];
    int pos = row_ptr[v] + atomicAdd(&cursor[v], 1);
    csr_src[pos] = src[e];
    csr_dst[pos] = v;
}

// ---------------- fs/fd GEMM: [N,K] @ [K,192] x2 ----------------
template <int K>
__global__ __launch_bounds__(256) void k_gemm_dual(const float* __restrict__ X,
                                                   const float* __restrict__ Ws,
                                                   const float* __restrict__ Wd,
                                                   float* __restrict__ FS,
                                                   float* __restrict__ FD) {
    __shared__ float xs[16][K];
    int tid = threadIdx.x;
    int row0 = blockIdx.x * 16;
    for (int idx = tid; idx < 16 * K; idx += 256) {
        int r = idx / K, k = idx - r * K;
        int row = row0 + r;
        xs[r][k] = (row < NN) ? X[(size_t)row * K + k] : 0.f;
    }
    __syncthreads();
    int tx = tid & 63;
    int ty = tid >> 6;  // 0..3 -> rows ty*4 .. ty*4+3
    float acc[4][6];
#pragma unroll
    for (int i = 0; i < 4; i++)
#pragma unroll
        for (int j = 0; j < 6; j++) acc[i][j] = 0.f;

    for (int k = 0; k < K; k++) {
        float w0 = Ws[k * HD + tx];
        float w1 = Ws[k * HD + tx + 64];
        float w2 = Ws[k * HD + tx + 128];
        float w3 = Wd[k * HD + tx];
        float w4 = Wd[k * HD + tx + 64];
        float w5 = Wd[k * HD + tx + 128];
#pragma unroll
        for (int i = 0; i < 4; i++) {
            float x = xs[ty * 4 + i][k];
            acc[i][0] += x * w0; acc[i][1] += x * w1; acc[i][2] += x * w2;
            acc[i][3] += x * w3; acc[i][4] += x * w4; acc[i][5] += x * w5;
        }
    }
#pragma unroll
    for (int i = 0; i < 4; i++) {
        int row = row0 + ty * 4 + i;
        if (row < NN) {
            size_t b = (size_t)row * HD;
            FS[b + tx] = acc[i][0]; FS[b + tx + 64] = acc[i][1]; FS[b + tx + 128] = acc[i][2];
            FD[b + tx] = acc[i][3]; FD[b + tx + 64] = acc[i][4]; FD[b + tx + 128] = acc[i][5];
        }
    }
}

// ---------------- per-edge attention logits (CSR order) ----------------
__global__ __launch_bounds__(256) void k_edge_logits(const int* __restrict__ csr_src,
                                                     const int* __restrict__ csr_dst,
                                                     const float* __restrict__ FS,
                                                     const float* __restrict__ FD,
                                                     const float* __restrict__ A,
                                                     float* __restrict__ logits) {
    int p = blockIdx.x * 4 + (threadIdx.x >> 6);
    if (p >= EE) return;
    int lane = threadIdx.x & 63;
    int u = csr_src[p], v = csr_dst[p];
    float a0 = A[lane], a1 = A[64 + lane], a2 = A[128 + lane];
    size_t bu = (size_t)u * HD, bv = (size_t)v * HD;
    float s0 = FS[bu + lane]       + FD[bv + lane];
    float s1 = FS[bu + 64 + lane]  + FD[bv + 64 + lane];
    float s2 = FS[bu + 128 + lane] + FD[bv + 128 + lane];
    s0 = s0 > 0.f ? s0 : 0.2f * s0;
    s1 = s1 > 0.f ? s1 : 0.2f * s1;
    s2 = s2 > 0.f ? s2 : 0.2f * s2;
    float l0 = wsum(s0 * a0), l1 = wsum(s1 * a1), l2 = wsum(s2 * a2);
    if (lane == 0) {
        logits[p * 3 + 0] = l0;
        logits[p * 3 + 1] = l1;
        logits[p * 3 + 2] = l2;
    }
}

// ---------------- per-node softmax stats (wave per node) ----------------
__global__ __launch_bounds__(256) void k_stats(const int* __restrict__ row_ptr,
                                               const float* __restrict__ logits,
                                               float* __restrict__ NM,
                                               float* __restrict__ NI) {
    int v = blockIdx.x * 4 + (threadIdx.x >> 6);
    if (v >= NN) return;
    int lane = threadIdx.x & 63;
    int start = row_ptr[v], end = row_ptr[v + 1];
    float m0 = -1e30f, m1 = -1e30f, m2 = -1e30f;
    for (int p = start + lane; p < end; p += 64) {
        m0 = fmaxf(m0, logits[p * 3 + 0]);
        m1 = fmaxf(m1, logits[p * 3 + 1]);
        m2 = fmaxf(m2, logits[p * 3 + 2]);
    }
    m0 = wmax(m0); m1 = wmax(m1); m2 = wmax(m2);
    float s0 = 0.f, s1 = 0.f, s2 = 0.f;
    for (int p = start + lane; p < end; p += 64) {
        s0 += expf(logits[p * 3 + 0] - m0);
        s1 += expf(logits[p * 3 + 1] - m1);
        s2 += expf(logits[p * 3 + 2] - m2);
    }
    s0 = wsum(s0); s1 = wsum(s1); s2 = wsum(s2);
    if (lane == 0) {
        NM[v * 3 + 0] = m0; NM[v * 3 + 1] = m1; NM[v * 3 + 2] = m2;
        NI[v * 3 + 0] = 1.f / fmaxf(s0, 1e-9f);
        NI[v * 3 + 1] = 1.f / fmaxf(s1, 1e-9f);
        NI[v * 3 + 2] = 1.f / fmaxf(s2, 1e-9f);
    }
}

// ---------------- per-edge alpha (edge-parallel, coalesced) ----------------
__global__ __launch_bounds__(256) void k_alpha(const int* __restrict__ csr_dst,
                                               const float* __restrict__ logits,
                                               const float* __restrict__ NM,
                                               const float* __restrict__ NI,
                                               float* __restrict__ ALPHA) {
    int p = blockIdx.x * 256 + threadIdx.x;
    if (p >= EE) return;
    int v = csr_dst[p];
    float m0 = NM[v * 3 + 0], m1 = NM[v * 3 + 1], m2 = NM[v * 3 + 2];
    float i0 = NI[v * 3 + 0], i1 = NI[v * 3 + 1], i2 = NI[v * 3 + 2];
    ALPHA[p * 3 + 0] = expf(logits[p * 3 + 0] - m0) * i0;
    ALPHA[p * 3 + 1] = expf(logits[p * 3 + 1] - m1) * i1;
    ALPHA[p * 3 + 2] = expf(logits[p * 3 + 2] - m2) * i2;
}

// ---------------- weighted gather-sum: one wave per (node, head) ----------------
__device__ inline float agg_unit(int v, int h, int lane,
                                 const int* __restrict__ row_ptr,
                                 const int* __restrict__ csr_src,
                                 const float* __restrict__ ALPHA,
                                 const float* __restrict__ FS,
                                 int* idx_s, float* al_s) {
    int start = row_ptr[v], end = row_ptr[v + 1];
    int deg = end - start;
    int dmin = deg < 64 ? deg : 64;
    if (lane < dmin) {
        int p = start + lane;
        idx_s[lane] = csr_src[p];
        al_s[lane] = ALPHA[p * 3 + h];
    }
    int f = h * 64 + lane;
    float acc = 0.f;
    int e = 0;
    for (; e + 4 <= dmin; e += 4) {
        int i0 = idx_s[e], i1 = idx_s[e + 1], i2 = idx_s[e + 2], i3 = idx_s[e + 3];
        float a0 = al_s[e], a1 = al_s[e + 1], a2 = al_s[e + 2], a3 = al_s[e + 3];
        float f0 = FS[(size_t)i0 * HD + f];
        float f1 = FS[(size_t)i1 * HD + f];
        float f2 = FS[(size_t)i2 * HD + f];
        float f3 = FS[(size_t)i3 * HD + f];
        acc = fmaf(a0, f0, acc); acc = fmaf(a1, f1, acc);
        acc = fmaf(a2, f2, acc); acc = fmaf(a3, f3, acc);
    }
    for (; e < dmin; e++)
        acc = fmaf(al_s[e], FS[(size_t)idx_s[e] * HD + f], acc);
    // rare tail: degree > 64
    for (int p = start + 64; p < end; p++)
        acc = fmaf(ALPHA[p * 3 + h], FS[(size_t)csr_src[p] * HD + f], acc);
    return acc;
}

__global__ __launch_bounds__(256) void k_aggregate2(const int* __restrict__ row_ptr,
                                                    const int* __restrict__ csr_src,
                                                    const float* __restrict__ ALPHA,
                                                    const float* __restrict__ FS,
                                                    const float* __restrict__ bias,
                                                    float* __restrict__ OUT) {
    __shared__ int idx_s[4][64];
    __shared__ float al_s[4][64];
    int wid = threadIdx.x >> 6;
    int unit = blockIdx.x * 4 + wid;
    if (unit >= NN * 3) return;
    int v = unit / 3;
    int h = unit - v * 3;
    int lane = threadIdx.x & 63;
    float acc = agg_unit(v, h, lane, row_ptr, csr_src, ALPHA, FS, idx_s[wid], al_s[wid]);
    int f = h * 64 + lane;
    OUT[(size_t)v * HD + f] = acc + bias[f];
}

// final layer: block per node (3 waves = 3 heads), head-mean + graph atomic
__global__ __launch_bounds__(192) void k_aggregate_final(const int* __restrict__ row_ptr,
                                                         const int* __restrict__ csr_src,
                                                         const float* __restrict__ ALPHA,
                                                         const float* __restrict__ FS,
                                                         const float* __restrict__ bias,
                                                         const int* __restrict__ graph_ids,
                                                         float* __restrict__ gsum,
                                                         int* __restrict__ gcnt) {
    __shared__ int idx_s[3][64];
    __shared__ float al_s[3][64];
    __shared__ float comb[3][64];
    int v = blockIdx.x;
    int h = threadIdx.x >> 6;
    int lane = threadIdx.x & 63;
    float acc = agg_unit(v, h, lane, row_ptr, csr_src, ALPHA, FS, idx_s[h], al_s[h]);
    comb[h][lane] = acc + bias[h * 64 + lane];
    __syncthreads();
    if (h == 0) {
        float val = (comb[0][lane] + comb[1][lane] + comb[2][lane]) * (1.f / 3.f);
        int g = graph_ids[v];
        atomicAdd(&gsum[g * 64 + lane], val);
        if (lane == 0) atomicAdd(&gcnt[g], 1);
    }
}

// ---------------- head: graph mean + pattern branch + classifier ----------------
__global__ __launch_bounds__(256) void k_head(const float* __restrict__ gsum, const int* __restrict__ gcnt,
                                              const float* __restrict__ p1, const float* __restrict__ p2,
                                              const float* __restrict__ p3,
                                              const float* __restrict__ Wex, const float* __restrict__ bex,
                                              const float* __restrict__ Wpat, const float* __restrict__ bpat,
                                              const float* __restrict__ Wc1, const float* __restrict__ bc1,
                                              const float* __restrict__ Wc2, const float* __restrict__ bc2,
                                              const float* __restrict__ Wc3, const float* __restrict__ bc3,
                                              float* __restrict__ out) {
    __shared__ float EX[64 * 96];    // reused for T1 (4096) + T2 (2048)
    __shared__ float XC[64 * 128];
    int tid = threadIdx.x;
    for (int idx = tid; idx < 64 * 96; idx += 256) {
        int g = idx / 96, j = idx - g * 96;
        const float* pp = (j < 32) ? p1 : ((j < 64) ? p2 : p3);
        int jj = j & 31;
        float acc = bex[jj];
        for (int k = 0; k < 64; k++) acc += pp[g * 64 + k] * Wex[k * 32 + jj];
        EX[idx] = acc;
    }
    for (int idx = tid; idx < 64 * 64; idx += 256) {
        int g = idx >> 6, d = idx & 63;
        float c = (float)gcnt[g];
        XC[g * 128 + d] = gsum[idx] / fmaxf(c, 1.f);
    }
    __syncthreads();
    for (int idx = tid; idx < 64 * 64; idx += 256) {
        int g = idx >> 6, j = idx & 63;
        float acc = bpat[j];
        for (int k = 0; k < 96; k++) acc += EX[g * 96 + k] * Wpat[k * 64 + j];
        XC[g * 128 + 64 + j] = acc > 0.f ? acc : 0.01f * acc;
    }
    __syncthreads();
    float* T1 = EX;
    for (int idx = tid; idx < 64 * 64; idx += 256) {
        int g = idx >> 6, j = idx & 63;
        float acc = bc1[j];
        for (int k = 0; k < 128; k++) acc += XC[g * 128 + k] * Wc1[k * 64 + j];
        T1[idx] = acc > 0.f ? acc : 0.01f * acc;
    }
    __syncthreads();
    float* T2 = EX + 4096;
    for (int idx = tid; idx < 64 * 32; idx += 256) {
        int g = idx >> 5, j = idx & 31;
        float acc = bc2[j];
        for (int k = 0; k < 64; k++) acc += T1[g * 64 + k] * Wc2[k * 32 + j];
        T2[idx] = acc > 0.f ? acc : 0.01f * acc;
    }
    __syncthreads();
    for (int idx = tid; idx < 64 * 2; idx += 256) {
        int g = idx >> 1, c = idx & 1;
        float acc = bc3[c];
        for (int k = 0; k < 32; k++) acc += T2[g * 32 + k] * Wc3[k * 2 + c];
        out[idx] = acc;
    }
}

extern "C" void kernel_launch(void* const* d_in, const int* in_sizes, int n_in,
                              void* d_out, int out_size, void* d_ws, size_t ws_size,
                              hipStream_t stream) {
    const float* X0  = (const float*)d_in[0];
    const int*   src = (const int*)d_in[1];
    const int*   dst = (const int*)d_in[2];
    const int*   gid = (const int*)d_in[3];
    const float* p1  = (const float*)d_in[4];
    const float* p2  = (const float*)d_in[5];
    const float* p3  = (const float*)d_in[6];
    const float* W1s = (const float*)d_in[7],  *W1d = (const float*)d_in[8];
    const float* a1  = (const float*)d_in[9],  *b1  = (const float*)d_in[10];
    const float* W2s = (const float*)d_in[11], *W2d = (const float*)d_in[12];
    const float* a2  = (const float*)d_in[13], *b2  = (const float*)d_in[14];
    const float* W3s = (const float*)d_in[15], *W3d = (const float*)d_in[16];
    const float* a3  = (const float*)d_in[17], *b3  = (const float*)d_in[18];
    const float* Wex = (const float*)d_in[19], *bex = (const float*)d_in[20];
    const float* Wpat= (const float*)d_in[21], *bpat= (const float*)d_in[22];
    const float* Wc1 = (const float*)d_in[23], *bc1 = (const float*)d_in[24];
    const float* Wc2 = (const float*)d_in[25], *bc2 = (const float*)d_in[26];
    const float* Wc3 = (const float*)d_in[27], *bc3 = (const float*)d_in[28];
    float* out = (float*)d_out;

    char* ws = (char*)d_ws;
    size_t off = 0;
    auto alloc = [&](size_t bytes) -> char* {
        char* p = ws + off;
        off = (off + bytes + 255) & ~(size_t)255;
        return p;
    };
    float* FS = (float*)alloc((size_t)NN * HD * 4);
    float* FD = (float*)alloc((size_t)NN * HD * 4);
    float* HA = (float*)alloc((size_t)NN * HD * 4);
    float* HB = (float*)alloc((size_t)NN * HD * 4);
    float* LG = (float*)alloc((size_t)EE * 3 * 4);
    float* ALPHA = (float*)alloc((size_t)EE * 3 * 4);
    float* NM = (float*)alloc((size_t)NN * 3 * 4);
    float* NI = (float*)alloc((size_t)NN * 3 * 4);
    int* row_ptr = (int*)alloc((size_t)(NN + 1) * 4);
    int* csr_src = (int*)alloc((size_t)EE * 4);
    int* csr_dst = (int*)alloc((size_t)EE * 4);
    int* bsums   = (int*)alloc(64 * 4);
    // zeroed region (one memset): counts | cursor | gsum | gcnt
    char* zbase = ws + off;
    int*   counts = (int*)alloc((size_t)NN * 4);
    int*   cursor = (int*)alloc((size_t)NN * 4);
    float* gsum   = (float*)alloc((size_t)GG * 64 * 4);
    int*   gcnt   = (int*)alloc((size_t)GG * 4);
    size_t zbytes = (size_t)((ws + off) - zbase);

    hipMemsetAsync(zbase, 0, zbytes, stream);

    int ebl = (EE + 255) / 256;
    int nb  = (NN + 1023) / 1024;
    k_count<<<ebl, 256, 0, stream>>>(dst, counts);
    k_scan_block<<<nb, 1024, 0, stream>>>(counts, row_ptr, bsums);
    k_scan_top<<<1, 64, 0, stream>>>(bsums, nb);
    k_scan_add<<<nb, 1024, 0, stream>>>(row_ptr, bsums);
    k_scatter<<<ebl, 256, 0, stream>>>(src, dst, row_ptr, cursor, csr_src, csr_dst);

    int gblk  = (NN + 15) / 16;
    int eblk4 = (EE + 3) / 4;
    int nblk4 = (NN + 3) / 4;
    int ublk  = (NN * 3 + 3) / 4;

    // layer 1 (K = 128)
    k_gemm_dual<128><<<gblk, 256, 0, stream>>>(X0, W1s, W1d, FS, FD);
    k_edge_logits<<<eblk4, 256, 0, stream>>>(csr_src, csr_dst, FS, FD, a1, LG);
    k_stats<<<nblk4, 256, 0, stream>>>(row_ptr, LG, NM, NI);
    k_alpha<<<ebl, 256, 0, stream>>>(csr_dst, LG, NM, NI, ALPHA);
    k_aggregate2<<<ublk, 256, 0, stream>>>(row_ptr, csr_src, ALPHA, FS, b1, HA);
    // layer 2 (K = 192)
    k_gemm_dual<192><<<gblk, 256, 0, stream>>>(HA, W2s, W2d, FS, FD);
    k_edge_logits<<<eblk4, 256, 0, stream>>>(csr_src, csr_dst, FS, FD, a2, LG);
    k_stats<<<nblk4, 256, 0, stream>>>(row_ptr, LG, NM, NI);
    k_alpha<<<ebl, 256, 0, stream>>>(csr_dst, LG, NM, NI, ALPHA);
    k_aggregate2<<<ublk, 256, 0, stream>>>(row_ptr, csr_src, ALPHA, FS, b2, HB);
    // layer 3 (K = 192), fused head-mean + graph-sum
    k_gemm_dual<192><<<gblk, 256, 0, stream>>>(HB, W3s, W3d, FS, FD);
    k_edge_logits<<<eblk4, 256, 0, stream>>>(csr_src, csr_dst, FS, FD, a3, LG);
    k_stats<<<nblk4, 256, 0, stream>>>(row_ptr, LG, NM, NI);
    k_alpha<<<ebl, 256, 0, stream>>>(csr_dst, LG, NM, NI, ALPHA);
    k_aggregate_final<<<NN, 192, 0, stream>>>(row_ptr, csr_src, ALPHA, FS, b3,
                                              gid, gsum, gcnt);

    k_head<<<1, 256, 0, stream>>>(gsum, gcnt, p1, p2, p3, Wex, bex, Wpat, bpat,
                                  Wc1, bc1, Wc2, bc2, Wc3, bc3, out);
}

// Round 3
// 1246.518 us; speedup vs baseline: 1.1743x; 1.1743x over previous
//
#include <hip/hip_runtime.h>
#include <cstdint>
#include <cstddef>

// Problem constants (fixed by the reference)
#define NN 50000
#define EE 400000
#define FIN 128
#define HH 3
#define DD 64
#define GG 64
#define PP 64
#define HD 192   // H*D

__device__ inline float wsum(float v) {
#pragma unroll
    for (int m = 32; m > 0; m >>= 1) v += __shfl_xor(v, m, 64);
    return v;
}

// ---------------- CSR build ----------------
__global__ void k_count(const int* __restrict__ dst, int* __restrict__ counts) {
    int e = blockIdx.x * 256 + threadIdx.x;
    if (e < EE) atomicAdd(&counts[dst[e]], 1);
}

__global__ void k_scan_block(const int* __restrict__ in, int* __restrict__ out,
                             int* __restrict__ bsums) {
    __shared__ int tmp[1024];
    int tid = threadIdx.x;
    int i = blockIdx.x * 1024 + tid;
    int v = (i < NN) ? in[i] : 0;
    tmp[tid] = v;
    __syncthreads();
    for (int off = 1; off < 1024; off <<= 1) {
        int t = (tid >= off) ? tmp[tid - off] : 0;
        __syncthreads();
        tmp[tid] += t;
        __syncthreads();
    }
    if (i < NN) out[i] = tmp[tid] - v;       // exclusive within block
    if (tid == 1023) bsums[blockIdx.x] = tmp[1023];
}

__global__ void k_scan_top(int* bsums, int nb) {
    int lane = threadIdx.x;
    int v = (lane < nb) ? bsums[lane] : 0;
    int x = v;
    for (int off = 1; off < 64; off <<= 1) {
        int t = __shfl_up(x, off, 64);
        if (lane >= off) x += t;
    }
    if (lane < nb) bsums[lane] = x - v;      // exclusive
}

__global__ void k_scan_add(int* __restrict__ row_ptr, const int* __restrict__ bsums) {
    int i = blockIdx.x * 1024 + threadIdx.x;
    if (i < NN) row_ptr[i] += bsums[blockIdx.x];
    if (blockIdx.x == 0 && threadIdx.x == 0) row_ptr[NN] = EE;
}

__global__ void k_scatter(const int* __restrict__ src, const int* __restrict__ dst,
                          const int* __restrict__ row_ptr, int* __restrict__ cursor,
                          int* __restrict__ csr_src) {
    int e = blockIdx.x * 256 + threadIdx.x;
    if (e >= EE) return;
    int v = dst[e];
    int pos = row_ptr[v] + atomicAdd(&cursor[v], 1);
    csr_src[pos] = src[e];
}

// ---------------- fs/fd GEMM: [N,K] @ [K,192] x2 ----------------
template <int K>
__global__ __launch_bounds__(256) void k_gemm_dual(const float* __restrict__ X,
                                                   const float* __restrict__ Ws,
                                                   const float* __restrict__ Wd,
                                                   float* __restrict__ FS,
                                                   float* __restrict__ FD) {
    __shared__ float xs[16][K];
    int tid = threadIdx.x;
    int row0 = blockIdx.x * 16;
    for (int idx = tid; idx < 16 * K; idx += 256) {
        int r = idx / K, k = idx - r * K;
        int row = row0 + r;
        xs[r][k] = (row < NN) ? X[(size_t)row * K + k] : 0.f;
    }
    __syncthreads();
    int tx = tid & 63;
    int ty = tid >> 6;  // 0..3 -> rows ty*4 .. ty*4+3
    float acc[4][6];
#pragma unroll
    for (int i = 0; i < 4; i++)
#pragma unroll
        for (int j = 0; j < 6; j++) acc[i][j] = 0.f;

    for (int k = 0; k < K; k++) {
        float w0 = Ws[k * HD + tx];
        float w1 = Ws[k * HD + tx + 64];
        float w2 = Ws[k * HD + tx + 128];
        float w3 = Wd[k * HD + tx];
        float w4 = Wd[k * HD + tx + 64];
        float w5 = Wd[k * HD + tx + 128];
#pragma unroll
        for (int i = 0; i < 4; i++) {
            float x = xs[ty * 4 + i][k];
            acc[i][0] += x * w0; acc[i][1] += x * w1; acc[i][2] += x * w2;
            acc[i][3] += x * w3; acc[i][4] += x * w4; acc[i][5] += x * w5;
        }
    }
#pragma unroll
    for (int i = 0; i < 4; i++) {
        int row = row0 + ty * 4 + i;
        if (row < NN) {
            size_t b = (size_t)row * HD;
            FS[b + tx] = acc[i][0]; FS[b + tx + 64] = acc[i][1]; FS[b + tx + 128] = acc[i][2];
            FD[b + tx] = acc[i][3]; FD[b + tx + 64] = acc[i][4]; FD[b + tx + 128] = acc[i][5];
        }
    }
}

// ---------------- fused GATv2 edge phase: logits + online softmax + aggregate ----
// One wave per node. fs[u] rows gathered ONCE per edge, kept in registers for
// both the logit reduction and the weighted accumulation (flash-style).
#define CHUNK 8
template <bool FINAL>
__global__ __launch_bounds__(256) void k_gat_fused(const int* __restrict__ row_ptr,
                                                   const int* __restrict__ csr_src,
                                                   const float* __restrict__ FS,
                                                   const float* __restrict__ FD,
                                                   const float* __restrict__ A,
                                                   const float* __restrict__ bias,
                                                   float* __restrict__ OUT,
                                                   const int* __restrict__ graph_ids,
                                                   float* __restrict__ gsum,
                                                   int* __restrict__ gcnt) {
    int v = blockIdx.x * 4 + (threadIdx.x >> 6);
    if (v >= NN) return;
    int lane = threadIdx.x & 63;
    int start = row_ptr[v], end = row_ptr[v + 1];
    size_t bv = (size_t)v * HD;
    float d0 = FD[bv + lane], d1 = FD[bv + 64 + lane], d2 = FD[bv + 128 + lane];
    float a0 = A[lane], a1 = A[64 + lane], a2 = A[128 + lane];

    float m0 = -1e30f, m1 = -1e30f, m2 = -1e30f;     // running max per head
    float l0 = 0.f, l1 = 0.f, l2 = 0.f;              // running denom per head
    float acc0 = 0.f, acc1 = 0.f, acc2 = 0.f;        // running weighted sum

    for (int p0 = start; p0 < end; p0 += CHUNK) {
        int cnt = end - p0;
        if (cnt > CHUNK) cnt = CHUNK;
        int my_idx = 0;
        if (lane < cnt) my_idx = csr_src[p0 + lane];

        float f0[CHUNK], f1[CHUNK], f2[CHUNK];
        // issue all gathers back-to-back: one memory phase per chunk
#pragma unroll
        for (int e = 0; e < CHUNK; e++) {
            if (e < cnt) {
                int u = __shfl(my_idx, e, 64);
                size_t bu = (size_t)u * HD;
                f0[e] = FS[bu + lane];
                f1[e] = FS[bu + 64 + lane];
                f2[e] = FS[bu + 128 + lane];
            } else {
                f0[e] = 0.f; f1[e] = 0.f; f2[e] = 0.f;
            }
        }
        float lg0[CHUNK], lg1[CHUNK], lg2[CHUNK];
#pragma unroll
        for (int e = 0; e < CHUNK; e++) {
            if (e < cnt) {
                float s0 = f0[e] + d0, s1 = f1[e] + d1, s2 = f2[e] + d2;
                s0 = s0 > 0.f ? s0 : 0.2f * s0;
                s1 = s1 > 0.f ? s1 : 0.2f * s1;
                s2 = s2 > 0.f ? s2 : 0.2f * s2;
                lg0[e] = wsum(s0 * a0);
                lg1[e] = wsum(s1 * a1);
                lg2[e] = wsum(s2 * a2);
            } else {
                lg0[e] = -1e30f; lg1[e] = -1e30f; lg2[e] = -1e30f;
            }
        }
        // chunk max per head
        float c0 = -1e30f, c1 = -1e30f, c2 = -1e30f;
#pragma unroll
        for (int e = 0; e < CHUNK; e++) {
            c0 = fmaxf(c0, lg0[e]); c1 = fmaxf(c1, lg1[e]); c2 = fmaxf(c2, lg2[e]);
        }
        float n0 = fmaxf(m0, c0), n1 = fmaxf(m1, c1), n2 = fmaxf(m2, c2);
        float sc0 = __expf(m0 - n0), sc1 = __expf(m1 - n1), sc2 = __expf(m2 - n2);
        acc0 *= sc0; l0 *= sc0;
        acc1 *= sc1; l1 *= sc1;
        acc2 *= sc2; l2 *= sc2;
#pragma unroll
        for (int e = 0; e < CHUNK; e++) {
            if (e < cnt) {
                float w0 = __expf(lg0[e] - n0);
                float w1 = __expf(lg1[e] - n1);
                float w2 = __expf(lg2[e] - n2);
                l0 += w0; l1 += w1; l2 += w2;
                acc0 = fmaf(w0, f0[e], acc0);
                acc1 = fmaf(w1, f1[e], acc1);
                acc2 = fmaf(w2, f2[e], acc2);
            }
        }
        m0 = n0; m1 = n1; m2 = n2;
    }

    float i0 = 1.f / fmaxf(l0, 1e-9f);
    float i1 = 1.f / fmaxf(l1, 1e-9f);
    float i2 = 1.f / fmaxf(l2, 1e-9f);
    if (!FINAL) {
        OUT[bv + lane]       = acc0 * i0 + bias[lane];
        OUT[bv + 64 + lane]  = acc1 * i1 + bias[64 + lane];
        OUT[bv + 128 + lane] = acc2 * i2 + bias[128 + lane];
    } else {
        float val = (acc0 * i0 + bias[lane] +
                     acc1 * i1 + bias[64 + lane] +
                     acc2 * i2 + bias[128 + lane]) * (1.f / 3.f);
        int g = graph_ids[v];
        atomicAdd(&gsum[g * 64 + lane], val);
        if (lane == 0) atomicAdd(&gcnt[g], 1);
    }
}

// ---------------- head: graph mean + pattern branch + classifier ----------------
__global__ __launch_bounds__(256) void k_head(const float* __restrict__ gsum, const int* __restrict__ gcnt,
                                              const float* __restrict__ p1, const float* __restrict__ p2,
                                              const float* __restrict__ p3,
                                              const float* __restrict__ Wex, const float* __restrict__ bex,
                                              const float* __restrict__ Wpat, const float* __restrict__ bpat,
                                              const float* __restrict__ Wc1, const float* __restrict__ bc1,
                                              const float* __restrict__ Wc2, const float* __restrict__ bc2,
                                              const float* __restrict__ Wc3, const float* __restrict__ bc3,
                                              float* __restrict__ out) {
    __shared__ float EX[64 * 96];    // reused for T1 (4096) + T2 (2048)
    __shared__ float XC[64 * 128];
    int tid = threadIdx.x;
    for (int idx = tid; idx < 64 * 96; idx += 256) {
        int g = idx / 96, j = idx - g * 96;
        const float* pp = (j < 32) ? p1 : ((j < 64) ? p2 : p3);
        int jj = j & 31;
        float acc = bex[jj];
        for (int k = 0; k < 64; k++) acc += pp[g * 64 + k] * Wex[k * 32 + jj];
        EX[idx] = acc;
    }
    for (int idx = tid; idx < 64 * 64; idx += 256) {
        int g = idx >> 6, d = idx & 63;
        float c = (float)gcnt[g];
        XC[g * 128 + d] = gsum[idx] / fmaxf(c, 1.f);
    }
    __syncthreads();
    for (int idx = tid; idx < 64 * 64; idx += 256) {
        int g = idx >> 6, j = idx & 63;
        float acc = bpat[j];
        for (int k = 0; k < 96; k++) acc += EX[g * 96 + k] * Wpat[k * 64 + j];
        XC[g * 128 + 64 + j] = acc > 0.f ? acc : 0.01f * acc;
    }
    __syncthreads();
    float* T1 = EX;
    for (int idx = tid; idx < 64 * 64; idx += 256) {
        int g = idx >> 6, j = idx & 63;
        float acc = bc1[j];
        for (int k = 0; k < 128; k++) acc += XC[g * 128 + k] * Wc1[k * 64 + j];
        T1[idx] = acc > 0.f ? acc : 0.01f * acc;
    }
    __syncthreads();
    float* T2 = EX + 4096;
    for (int idx = tid; idx < 64 * 32; idx += 256) {
        int g = idx >> 5, j = idx & 31;
        float acc = bc2[j];
        for (int k = 0; k < 64; k++) acc += T1[g * 64 + k] * Wc2[k * 32 + j];
        T2[idx] = acc > 0.f ? acc : 0.01f * acc;
    }
    __syncthreads();
    for (int idx = tid; idx < 64 * 2; idx += 256) {
        int g = idx >> 1, c = idx & 1;
        float acc = bc3[c];
        for (int k = 0; k < 32; k++) acc += T2[g * 32 + k] * Wc3[k * 2 + c];
        out[idx] = acc;
    }
}

extern "C" void kernel_launch(void* const* d_in, const int* in_sizes, int n_in,
                              void* d_out, int out_size, void* d_ws, size_t ws_size,
                              hipStream_t stream) {
    const float* X0  = (const float*)d_in[0];
    const int*   src = (const int*)d_in[1];
    const int*   dst = (const int*)d_in[2];
    const int*   gid = (const int*)d_in[3];
    const float* p1  = (const float*)d_in[4];
    const float* p2  = (const float*)d_in[5];
    const float* p3  = (const float*)d_in[6];
    const float* W1s = (const float*)d_in[7],  *W1d = (const float*)d_in[8];
    const float* a1  = (const float*)d_in[9],  *b1  = (const float*)d_in[10];
    const float* W2s = (const float*)d_in[11], *W2d = (const float*)d_in[12];
    const float* a2  = (const float*)d_in[13], *b2  = (const float*)d_in[14];
    const float* W3s = (const float*)d_in[15], *W3d = (const float*)d_in[16];
    const float* a3  = (const float*)d_in[17], *b3  = (const float*)d_in[18];
    const float* Wex = (const float*)d_in[19], *bex = (const float*)d_in[20];
    const float* Wpat= (const float*)d_in[21], *bpat= (const float*)d_in[22];
    const float* Wc1 = (const float*)d_in[23], *bc1 = (const float*)d_in[24];
    const float* Wc2 = (const float*)d_in[25], *bc2 = (const float*)d_in[26];
    const float* Wc3 = (const float*)d_in[27], *bc3 = (const float*)d_in[28];
    float* out = (float*)d_out;

    char* ws = (char*)d_ws;
    size_t off = 0;
    auto alloc = [&](size_t bytes) -> char* {
        char* p = ws + off;
        off = (off + bytes + 255) & ~(size_t)255;
        return p;
    };
    float* FS = (float*)alloc((size_t)NN * HD * 4);
    float* FD = (float*)alloc((size_t)NN * HD * 4);
    float* HA = (float*)alloc((size_t)NN * HD * 4);
    float* HB = (float*)alloc((size_t)NN * HD * 4);
    int* row_ptr = (int*)alloc((size_t)(NN + 1) * 4);
    int* csr_src = (int*)alloc((size_t)EE * 4);
    int* bsums   = (int*)alloc(64 * 4);
    // zeroed region (one memset): counts | cursor | gsum | gcnt
    char* zbase = ws + off;
    int*   counts = (int*)alloc((size_t)NN * 4);
    int*   cursor = (int*)alloc((size_t)NN * 4);
    float* gsum   = (float*)alloc((size_t)GG * 64 * 4);
    int*   gcnt   = (int*)alloc((size_t)GG * 4);
    size_t zbytes = (size_t)((ws + off) - zbase);

    hipMemsetAsync(zbase, 0, zbytes, stream);

    int ebl = (EE + 255) / 256;
    int nb  = (NN + 1023) / 1024;
    k_count<<<ebl, 256, 0, stream>>>(dst, counts);
    k_scan_block<<<nb, 1024, 0, stream>>>(counts, row_ptr, bsums);
    k_scan_top<<<1, 64, 0, stream>>>(bsums, nb);
    k_scan_add<<<nb, 1024, 0, stream>>>(row_ptr, bsums);
    k_scatter<<<ebl, 256, 0, stream>>>(src, dst, row_ptr, cursor, csr_src);

    int gblk  = (NN + 15) / 16;
    int nblk4 = (NN + 3) / 4;

    // layer 1 (K = 128)
    k_gemm_dual<128><<<gblk, 256, 0, stream>>>(X0, W1s, W1d, FS, FD);
    k_gat_fused<false><<<nblk4, 256, 0, stream>>>(row_ptr, csr_src, FS, FD, a1, b1, HA,
                                                  nullptr, nullptr, nullptr);
    // layer 2 (K = 192)
    k_gemm_dual<192><<<gblk, 256, 0, stream>>>(HA, W2s, W2d, FS, FD);
    k_gat_fused<false><<<nblk4, 256, 0, stream>>>(row_ptr, csr_src, FS, FD, a2, b2, HB,
                                                  nullptr, nullptr, nullptr);
    // layer 3 (K = 192), fused head-mean + graph-sum
    k_gemm_dual<192><<<gblk, 256, 0, stream>>>(HB, W3s, W3d, FS, FD);
    k_gat_fused<true><<<nblk4, 256, 0, stream>>>(row_ptr, csr_src, FS, FD, a3, b3, nullptr,
                                                 gid, gsum, gcnt);

    k_head<<<1, 256, 0, stream>>>(gsum, gcnt, p1, p2, p3, Wex, bex, Wpat, bpat,
                                  Wc1, bc1, Wc2, bc2, Wc3, bc3, out);
}

// Round 4
// 1239.039 us; speedup vs baseline: 1.1814x; 1.0060x over previous
//
#include <hip/hip_runtime.h>
#include <cstdint>
#include <cstddef>

// Problem constants (fixed by the reference)
#define NN 50000
#define EE 400000
#define FIN 128
#define HH 3
#define DD 64
#define GG 64
#define PP 64
#define HD 192   // H*D

__device__ inline float wsum(float v) {
#pragma unroll
    for (int m = 32; m > 0; m >>= 1) v += __shfl_xor(v, m, 64);
    return v;
}

// bf16 <-> f32 (RNE)
__device__ inline float bf2f(unsigned short u) {
    union { unsigned int i; float f; } x; x.i = ((unsigned int)u) << 16; return x.f;
}
__device__ inline unsigned short f2bf(float f) {
    union { float f; unsigned int i; } x; x.f = f;
    unsigned int r = x.i + 0x7FFFu + ((x.i >> 16) & 1u);
    return (unsigned short)(r >> 16);
}

// ---------------- CSR build ----------------
__global__ void k_count(const int* __restrict__ dst, int* __restrict__ counts) {
    int e = blockIdx.x * 256 + threadIdx.x;
    if (e < EE) atomicAdd(&counts[dst[e]], 1);
}

__global__ void k_scan_block(const int* __restrict__ in, int* __restrict__ out,
                             int* __restrict__ bsums) {
    __shared__ int tmp[1024];
    int tid = threadIdx.x;
    int i = blockIdx.x * 1024 + tid;
    int v = (i < NN) ? in[i] : 0;
    tmp[tid] = v;
    __syncthreads();
    for (int off = 1; off < 1024; off <<= 1) {
        int t = (tid >= off) ? tmp[tid - off] : 0;
        __syncthreads();
        tmp[tid] += t;
        __syncthreads();
    }
    if (i < NN) out[i] = tmp[tid] - v;       // exclusive within block
    if (tid == 1023) bsums[blockIdx.x] = tmp[1023];
}

__global__ void k_scan_top(int* bsums, int nb) {
    int lane = threadIdx.x;
    int v = (lane < nb) ? bsums[lane] : 0;
    int x = v;
    for (int off = 1; off < 64; off <<= 1) {
        int t = __shfl_up(x, off, 64);
        if (lane >= off) x += t;
    }
    if (lane < nb) bsums[lane] = x - v;      // exclusive
}

__global__ void k_scan_add(int* __restrict__ row_ptr, const int* __restrict__ bsums) {
    int i = blockIdx.x * 1024 + threadIdx.x;
    if (i < NN) row_ptr[i] += bsums[blockIdx.x];
    if (blockIdx.x == 0 && threadIdx.x == 0) row_ptr[NN] = EE;
}

__global__ void k_scatter(const int* __restrict__ src, const int* __restrict__ dst,
                          const int* __restrict__ row_ptr, int* __restrict__ cursor,
                          int* __restrict__ csr_src) {
    int e = blockIdx.x * 256 + threadIdx.x;
    if (e >= EE) return;
    int v = dst[e];
    int pos = row_ptr[v] + atomicAdd(&cursor[v], 1);
    csr_src[pos] = src[e];
}

// ---------------- fs/fd GEMM: [N,K] @ [K,192] x2; FS stored bf16 ----------------
template <int K>
__global__ __launch_bounds__(256) void k_gemm_dual(const float* __restrict__ X,
                                                   const float* __restrict__ Ws,
                                                   const float* __restrict__ Wd,
                                                   unsigned short* __restrict__ FS,
                                                   float* __restrict__ FD) {
    __shared__ float xs[16][K];
    int tid = threadIdx.x;
    int row0 = blockIdx.x * 16;
    for (int idx = tid; idx < 16 * K; idx += 256) {
        int r = idx / K, k = idx - r * K;
        int row = row0 + r;
        xs[r][k] = (row < NN) ? X[(size_t)row * K + k] : 0.f;
    }
    __syncthreads();
    int tx = tid & 63;
    int ty = tid >> 6;  // 0..3 -> rows ty*4 .. ty*4+3
    float acc[4][6];
#pragma unroll
    for (int i = 0; i < 4; i++)
#pragma unroll
        for (int j = 0; j < 6; j++) acc[i][j] = 0.f;

    for (int k = 0; k < K; k++) {
        float w0 = Ws[k * HD + tx];
        float w1 = Ws[k * HD + tx + 64];
        float w2 = Ws[k * HD + tx + 128];
        float w3 = Wd[k * HD + tx];
        float w4 = Wd[k * HD + tx + 64];
        float w5 = Wd[k * HD + tx + 128];
#pragma unroll
        for (int i = 0; i < 4; i++) {
            float x = xs[ty * 4 + i][k];
            acc[i][0] += x * w0; acc[i][1] += x * w1; acc[i][2] += x * w2;
            acc[i][3] += x * w3; acc[i][4] += x * w4; acc[i][5] += x * w5;
        }
    }
#pragma unroll
    for (int i = 0; i < 4; i++) {
        int row = row0 + ty * 4 + i;
        if (row < NN) {
            size_t b = (size_t)row * HD;
            FS[b + tx] = f2bf(acc[i][0]);
            FS[b + tx + 64] = f2bf(acc[i][1]);
            FS[b + tx + 128] = f2bf(acc[i][2]);
            FD[b + tx] = acc[i][3]; FD[b + tx + 64] = acc[i][4]; FD[b + tx + 128] = acc[i][5];
        }
    }
}

// ---------------- fused GATv2 edge phase: logits + online softmax + aggregate ----
// One wave per node. fs[u] (bf16) gathered ONCE per edge, kept in registers for
// both the logit reduction and the weighted accumulation (flash-style).
#define CHUNK 8
template <bool FINAL>
__global__ __launch_bounds__(256) void k_gat_fused(const int* __restrict__ row_ptr,
                                                   const int* __restrict__ csr_src,
                                                   const unsigned short* __restrict__ FS,
                                                   const float* __restrict__ FD,
                                                   const float* __restrict__ A,
                                                   const float* __restrict__ bias,
                                                   float* __restrict__ OUT,
                                                   const int* __restrict__ graph_ids,
                                                   float* __restrict__ gsum,
                                                   int* __restrict__ gcnt) {
    int v = blockIdx.x * 4 + (threadIdx.x >> 6);
    if (v >= NN) return;
    int lane = threadIdx.x & 63;
    int start = row_ptr[v], end = row_ptr[v + 1];
    size_t bv = (size_t)v * HD;
    float d0 = FD[bv + lane], d1 = FD[bv + 64 + lane], d2 = FD[bv + 128 + lane];
    float a0 = A[lane], a1 = A[64 + lane], a2 = A[128 + lane];

    float m0 = -1e30f, m1 = -1e30f, m2 = -1e30f;     // running max per head
    float l0 = 0.f, l1 = 0.f, l2 = 0.f;              // running denom per head
    float acc0 = 0.f, acc1 = 0.f, acc2 = 0.f;        // running weighted sum

    for (int p0 = start; p0 < end; p0 += CHUNK) {
        int cnt = end - p0;
        if (cnt > CHUNK) cnt = CHUNK;
        int my_idx = 0;
        if (lane < cnt) my_idx = csr_src[p0 + lane];

        float f0[CHUNK], f1[CHUNK], f2[CHUNK];
        // issue all gathers back-to-back: one memory phase per chunk
#pragma unroll
        for (int e = 0; e < CHUNK; e++) {
            if (e < cnt) {
                int u = __shfl(my_idx, e, 64);
                size_t bu = (size_t)u * HD;
                f0[e] = bf2f(FS[bu + lane]);
                f1[e] = bf2f(FS[bu + 64 + lane]);
                f2[e] = bf2f(FS[bu + 128 + lane]);
            } else {
                f0[e] = 0.f; f1[e] = 0.f; f2[e] = 0.f;
            }
        }
        float lg0[CHUNK], lg1[CHUNK], lg2[CHUNK];
#pragma unroll
        for (int e = 0; e < CHUNK; e++) {
            if (e < cnt) {
                float s0 = f0[e] + d0, s1 = f1[e] + d1, s2 = f2[e] + d2;
                s0 = s0 > 0.f ? s0 : 0.2f * s0;
                s1 = s1 > 0.f ? s1 : 0.2f * s1;
                s2 = s2 > 0.f ? s2 : 0.2f * s2;
                lg0[e] = wsum(s0 * a0);
                lg1[e] = wsum(s1 * a1);
                lg2[e] = wsum(s2 * a2);
            } else {
                lg0[e] = -1e30f; lg1[e] = -1e30f; lg2[e] = -1e30f;
            }
        }
        // chunk max per head
        float c0 = -1e30f, c1 = -1e30f, c2 = -1e30f;
#pragma unroll
        for (int e = 0; e < CHUNK; e++) {
            c0 = fmaxf(c0, lg0[e]); c1 = fmaxf(c1, lg1[e]); c2 = fmaxf(c2, lg2[e]);
        }
        float n0 = fmaxf(m0, c0), n1 = fmaxf(m1, c1), n2 = fmaxf(m2, c2);
        float sc0 = __expf(m0 - n0), sc1 = __expf(m1 - n1), sc2 = __expf(m2 - n2);
        acc0 *= sc0; l0 *= sc0;
        acc1 *= sc1; l1 *= sc1;
        acc2 *= sc2; l2 *= sc2;
#pragma unroll
        for (int e = 0; e < CHUNK; e++) {
            if (e < cnt) {
                float w0 = __expf(lg0[e] - n0);
                float w1 = __expf(lg1[e] - n1);
                float w2 = __expf(lg2[e] - n2);
                l0 += w0; l1 += w1; l2 += w2;
                acc0 = fmaf(w0, f0[e], acc0);
                acc1 = fmaf(w1, f1[e], acc1);
                acc2 = fmaf(w2, f2[e], acc2);
            }
        }
        m0 = n0; m1 = n1; m2 = n2;
    }

    float i0 = 1.f / fmaxf(l0, 1e-9f);
    float i1 = 1.f / fmaxf(l1, 1e-9f);
    float i2 = 1.f / fmaxf(l2, 1e-9f);
    if (!FINAL) {
        OUT[bv + lane]       = acc0 * i0 + bias[lane];
        OUT[bv + 64 + lane]  = acc1 * i1 + bias[64 + lane];
        OUT[bv + 128 + lane] = acc2 * i2 + bias[128 + lane];
    } else {
        float val = (acc0 * i0 + bias[lane] +
                     acc1 * i1 + bias[64 + lane] +
                     acc2 * i2 + bias[128 + lane]) * (1.f / 3.f);
        int g = graph_ids[v];
        atomicAdd(&gsum[g * 64 + lane], val);
        if (lane == 0) atomicAdd(&gcnt[g], 1);
    }
}

// ---------------- head: graph mean + pattern branch + classifier ----------------
__global__ __launch_bounds__(256) void k_head(const float* __restrict__ gsum, const int* __restrict__ gcnt,
                                              const float* __restrict__ p1, const float* __restrict__ p2,
                                              const float* __restrict__ p3,
                                              const float* __restrict__ Wex, const float* __restrict__ bex,
                                              const float* __restrict__ Wpat, const float* __restrict__ bpat,
                                              const float* __restrict__ Wc1, const float* __restrict__ bc1,
                                              const float* __restrict__ Wc2, const float* __restrict__ bc2,
                                              const float* __restrict__ Wc3, const float* __restrict__ bc3,
                                              float* __restrict__ out) {
    __shared__ float EX[64 * 96];    // reused for T1 (4096) + T2 (2048)
    __shared__ float XC[64 * 128];
    int tid = threadIdx.x;
    for (int idx = tid; idx < 64 * 96; idx += 256) {
        int g = idx / 96, j = idx - g * 96;
        const float* pp = (j < 32) ? p1 : ((j < 64) ? p2 : p3);
        int jj = j & 31;
        float acc = bex[jj];
        for (int k = 0; k < 64; k++) acc += pp[g * 64 + k] * Wex[k * 32 + jj];
        EX[idx] = acc;
    }
    for (int idx = tid; idx < 64 * 64; idx += 256) {
        int g = idx >> 6, d = idx & 63;
        float c = (float)gcnt[g];
        XC[g * 128 + d] = gsum[idx] / fmaxf(c, 1.f);
    }
    __syncthreads();
    for (int idx = tid; idx < 64 * 64; idx += 256) {
        int g = idx >> 6, j = idx & 63;
        float acc = bpat[j];
        for (int k = 0; k < 96; k++) acc += EX[g * 96 + k] * Wpat[k * 64 + j];
        XC[g * 128 + 64 + j] = acc > 0.f ? acc : 0.01f * acc;
    }
    __syncthreads();
    float* T1 = EX;
    for (int idx = tid; idx < 64 * 64; idx += 256) {
        int g = idx >> 6, j = idx & 63;
        float acc = bc1[j];
        for (int k = 0; k < 128; k++) acc += XC[g * 128 + k] * Wc1[k * 64 + j];
        T1[idx] = acc > 0.f ? acc : 0.01f * acc;
    }
    __syncthreads();
    float* T2 = EX + 4096;
    for (int idx = tid; idx < 64 * 32; idx += 256) {
        int g = idx >> 5, j = idx & 31;
        float acc = bc2[j];
        for (int k = 0; k < 64; k++) acc += T1[g * 64 + k] * Wc2[k * 32 + j];
        T2[idx] = acc > 0.f ? acc : 0.01f * acc;
    }
    __syncthreads();
    for (int idx = tid; idx < 64 * 2; idx += 256) {
        int g = idx >> 1, c = idx & 1;
        float acc = bc3[c];
        for (int k = 0; k < 32; k++) acc += T2[g * 32 + k] * Wc3[k * 2 + c];
        out[idx] = acc;
    }
}

extern "C" void kernel_launch(void* const* d_in, const int* in_sizes, int n_in,
                              void* d_out, int out_size, void* d_ws, size_t ws_size,
                              hipStream_t stream) {
    const float* X0  = (const float*)d_in[0];
    const int*   src = (const int*)d_in[1];
    const int*   dst = (const int*)d_in[2];
    const int*   gid = (const int*)d_in[3];
    const float* p1  = (const float*)d_in[4];
    const float* p2  = (const float*)d_in[5];
    const float* p3  = (const float*)d_in[6];
    const float* W1s = (const float*)d_in[7],  *W1d = (const float*)d_in[8];
    const float* a1  = (const float*)d_in[9],  *b1  = (const float*)d_in[10];
    const float* W2s = (const float*)d_in[11], *W2d = (const float*)d_in[12];
    const float* a2  = (const float*)d_in[13], *b2  = (const float*)d_in[14];
    const float* W3s = (const float*)d_in[15], *W3d = (const float*)d_in[16];
    const float* a3  = (const float*)d_in[17], *b3  = (const float*)d_in[18];
    const float* Wex = (const float*)d_in[19], *bex = (const float*)d_in[20];
    const float* Wpat= (const float*)d_in[21], *bpat= (const float*)d_in[22];
    const float* Wc1 = (const float*)d_in[23], *bc1 = (const float*)d_in[24];
    const float* Wc2 = (const float*)d_in[25], *bc2 = (const float*)d_in[26];
    const float* Wc3 = (const float*)d_in[27], *bc3 = (const float*)d_in[28];
    float* out = (float*)d_out;

    char* ws = (char*)d_ws;
    size_t off = 0;
    auto alloc = [&](size_t bytes) -> char* {
        char* p = ws + off;
        off = (off + bytes + 255) & ~(size_t)255;
        return p;
    };
    unsigned short* FS = (unsigned short*)alloc((size_t)NN * HD * 2);  // bf16
    float* FD = (float*)alloc((size_t)NN * HD * 4);
    float* HA = (float*)alloc((size_t)NN * HD * 4);
    float* HB = (float*)alloc((size_t)NN * HD * 4);
    int* row_ptr = (int*)alloc((size_t)(NN + 1) * 4);
    int* csr_src = (int*)alloc((size_t)EE * 4);
    int* bsums   = (int*)alloc(64 * 4);
    // zeroed region (one memset): counts | cursor | gsum | gcnt
    char* zbase = ws + off;
    int*   counts = (int*)alloc((size_t)NN * 4);
    int*   cursor = (int*)alloc((size_t)NN * 4);
    float* gsum   = (float*)alloc((size_t)GG * 64 * 4);
    int*   gcnt   = (int*)alloc((size_t)GG * 4);
    size_t zbytes = (size_t)((ws + off) - zbase);

    hipMemsetAsync(zbase, 0, zbytes, stream);

    int ebl = (EE + 255) / 256;
    int nb  = (NN + 1023) / 1024;
    k_count<<<ebl, 256, 0, stream>>>(dst, counts);
    k_scan_block<<<nb, 1024, 0, stream>>>(counts, row_ptr, bsums);
    k_scan_top<<<1, 64, 0, stream>>>(bsums, nb);
    k_scan_add<<<nb, 1024, 0, stream>>>(row_ptr, bsums);
    k_scatter<<<ebl, 256, 0, stream>>>(src, dst, row_ptr, cursor, csr_src);

    int gblk  = (NN + 15) / 16;
    int nblk4 = (NN + 3) / 4;

    // layer 1 (K = 128)
    k_gemm_dual<128><<<gblk, 256, 0, stream>>>(X0, W1s, W1d, FS, FD);
    k_gat_fused<false><<<nblk4, 256, 0, stream>>>(row_ptr, csr_src, FS, FD, a1, b1, HA,
                                                  nullptr, nullptr, nullptr);
    // layer 2 (K = 192)
    k_gemm_dual<192><<<gblk, 256, 0, stream>>>(HA, W2s, W2d, FS, FD);
    k_gat_fused<false><<<nblk4, 256, 0, stream>>>(row_ptr, csr_src, FS, FD, a2, b2, HB,
                                                  nullptr, nullptr, nullptr);
    // layer 3 (K = 192), fused head-mean + graph-sum
    k_gemm_dual<192><<<gblk, 256, 0, stream>>>(HB, W3s, W3d, FS, FD);
    k_gat_fused<true><<<nblk4, 256, 0, stream>>>(row_ptr, csr_src, FS, FD, a3, b3, nullptr,
                                                 gid, gsum, gcnt);

    k_head<<<1, 256, 0, stream>>>(gsum, gcnt, p1, p2, p3, Wex, bex, Wpat, bpat,
                                  Wc1, bc1, Wc2, bc2, Wc3, bc3, out);
}